// Round 1
// baseline (1076.677 us; speedup 1.0000x reference)
//
#include <hip/hip_runtime.h>
#include <math.h>

// DSA sparse attention, MI355X. Round 1: correctness-first fp32 pipeline.
// Stages: [k1] indexer proj + LN -> [k2] fp32 S x S relu-weighted scores +
// exact top-256 radix select -> [k3] gathered 8-head attention.

#define B_   2
#define S_   4096
#define DM_  1024
#define HQ_  8
#define TK_  256

typedef unsigned int u32;
typedef unsigned long long u64;

__device__ __forceinline__ float dot4(const float4 a, const float4 b) {
    return a.x*b.x + a.y*b.y + a.z*b.z + a.w*b.w;
}
// monotonic float->uint key (handles any sign; scores are >=0 here)
__device__ __forceinline__ u32 fkey(float f) {
    u32 b = __float_as_uint(f);
    return (b & 0x80000000u) ? ~b : (b | 0x80000000u);
}

// ---------------- Kernel 1: indexer projections + LayerNorm ----------------
// 16 rows/block, 256 thr. Thread owns output col o (0..63) for BOTH Wq and Wk,
// 4 rows (rh = tid>>6). LN over 32-wide groups via width-32 shuffles.
__global__ __launch_bounds__(256) void k_proj_ln(
    const float* __restrict__ x,
    const float* __restrict__ Wq, const float* __restrict__ bq,
    const float* __restrict__ Wk, const float* __restrict__ bk,
    const float* __restrict__ lg, const float* __restrict__ lb,
    float* __restrict__ qi, float* __restrict__ ki)
{
    __shared__ float xs[16*64];
    const int tid = threadIdx.x;
    const int o   = tid & 63;
    const int rh  = tid >> 6;
    const size_t r0 = (size_t)blockIdx.x * 16;

    float acc[2][4];
    #pragma unroll
    for (int j = 0; j < 2; ++j)
        #pragma unroll
        for (int r = 0; r < 4; ++r) acc[j][r] = 0.f;

    const float* wqr = Wq + (size_t)o * DM_;
    const float* wkr = Wk + (size_t)o * DM_;

    for (int kt = 0; kt < 16; ++kt) {
        {
            const int row = tid >> 4, c4 = (tid & 15) << 2;
            *(float4*)&xs[row*64 + c4] =
                *(const float4*)&x[(r0 + row) * DM_ + kt*64 + c4];
        }
        __syncthreads();
        #pragma unroll
        for (int k8 = 0; k8 < 8; ++k8) {
            const int base = kt*64 + k8*8;
            const float4 wq0 = *(const float4*)&wqr[base];
            const float4 wq1 = *(const float4*)&wqr[base+4];
            const float4 wk0 = *(const float4*)&wkr[base];
            const float4 wk1 = *(const float4*)&wkr[base+4];
            #pragma unroll
            for (int rr = 0; rr < 4; ++rr) {
                const float* xr = &xs[(rh*4+rr)*64 + k8*8];
                const float4 xa = *(const float4*)xr;
                const float4 xb = *(const float4*)(xr+4);
                acc[0][rr] += dot4(wq0,xa) + dot4(wq1,xb);
                acc[1][rr] += dot4(wk0,xa) + dot4(wk1,xb);
            }
        }
        __syncthreads();
    }

    const float bqv = bq[o], bkv = bk[o];
    const float gv = lg[o & 31], bv = lb[o & 31];
    #pragma unroll
    for (int j = 0; j < 2; ++j) {
        #pragma unroll
        for (int rr = 0; rr < 4; ++rr) {
            float v = acc[j][rr] + (j == 0 ? bqv : bkv);
            float s = v;
            #pragma unroll
            for (int off = 16; off >= 1; off >>= 1) s += __shfl_xor(s, off, 32);
            const float m = s * (1.f/32.f);
            const float d = v - m;
            float s2 = d * d;
            #pragma unroll
            for (int off = 16; off >= 1; off >>= 1) s2 += __shfl_xor(s2, off, 32);
            const float var = s2 * (1.f/32.f);
            const float ov = d * rsqrtf(var + 1e-5f) * gv + bv;
            const size_t row = r0 + rh*4 + rr;
            if (j == 0) qi[row*64 + o] = ov;
            else        ki[row*64 + o] = ov;
        }
    }
}

// ---------------- Kernel 2: pairwise scores + exact top-256 ----------------
// 8 score-rows (s) per block, 512 thr (8 waves). Wave w computes ALL 8 rows
// for t in [w*512,(w+1)*512). Scores live in LDS [8][4096] fp32.
// Then wave w radix-selects row w (4x8-bit passes, LDS histogram), and
// emits the exact top-256 set (ties at threshold: lowest index, jax-stable).
__global__ __launch_bounds__(512) void k_score_topk(
    const float* __restrict__ qi, const float* __restrict__ ki,
    const float* __restrict__ idxw, int* __restrict__ top)
{
    extern __shared__ float smem[];
    float* sc   = smem;                         // [8][4096]
    float* kl   = smem + 8*4096;                // [8][64]
    u32*   hist = (u32*)(smem + 8*4096 + 8*64); // [8][256]
    int*   selw = (int*)(hist + 8*256);         // [8][2]

    const int tid  = threadIdx.x;
    const int w    = tid >> 6, lane = tid & 63;
    const int b    = blockIdx.x >> 9;
    const int s0   = (blockIdx.x & 511) << 3;
    const float w0 = idxw[0], w1 = idxw[1];

    { // stage k_i rows
        const int r = tid >> 6, c = tid & 63;
        kl[r*64 + c] = ki[((size_t)(b*S_ + s0 + r))*64 + c];
    }
    __syncthreads();

    // ---- scores ----
    for (int it = 0; it < 8; ++it) {
        const int t = (w << 9) + (it << 6) + lane;
        const float* qrow = qi + ((size_t)(b*S_ + t)) * 64;
        float a[8][2];
        #pragma unroll
        for (int r = 0; r < 8; ++r) { a[r][0] = 0.f; a[r][1] = 0.f; }
        #pragma unroll
        for (int hh = 0; hh < 2; ++hh) {
            float4 q[8];
            #pragma unroll
            for (int u = 0; u < 8; ++u)
                q[u] = *(const float4*)&qrow[hh*32 + u*4];
            #pragma unroll
            for (int r = 0; r < 8; ++r) {
                float s = 0.f;
                #pragma unroll
                for (int u = 0; u < 8; ++u) {
                    const float4 k4 = *(const float4*)&kl[r*64 + hh*32 + u*4];
                    s += dot4(q[u], k4);
                }
                a[r][hh] = s;
            }
        }
        #pragma unroll
        for (int r = 0; r < 8; ++r)
            sc[r*4096 + t] = w0 * fmaxf(a[r][0], 0.f) + w1 * fmaxf(a[r][1], 0.f);
    }
    __syncthreads();

    // ---- radix select: wave w owns row w ----
    const float* srow = sc + w*4096;
    u32* hw = hist + w*256;
    u32 prefix = 0; int krem = TK_;
    #pragma unroll 1
    for (int pass = 0; pass < 4; ++pass) {
        const int shift = 24 - 8*pass;
        for (int j2 = lane; j2 < 256; j2 += 64) hw[j2] = 0;
        __syncthreads();
        for (int i = 0; i < 64; ++i) {
            const u32 key = fkey(srow[i*64 + lane]);
            const bool ok = (pass == 0) || ((key >> (shift + 8)) == prefix);
            if (ok) atomicAdd(&hw[(key >> shift) & 255], 1u);
        }
        __syncthreads();
        if (lane == 0) {
            u32 cum = 0; int bsel = 0; int nk = krem;
            for (int bin = 255; bin >= 0; --bin) {
                const u32 c = hw[bin];
                if (cum + c >= (u32)krem) { bsel = bin; nk = krem - (int)cum; break; }
                cum += c;
            }
            selw[w*2] = bsel; selw[w*2+1] = nk;
        }
        __syncthreads();
        prefix = (prefix << 8) | (u32)selw[w*2];
        krem   = selw[w*2+1];
    }

    // ---- collect: > T all; == T lowest indices up to krem ----
    const u32 T = prefix;
    const int G = TK_ - krem;
    const u64 lmask = (lane == 0) ? 0ull : ((~0ull) >> (64 - lane));
    int cgt = 0, ceq = 0;
    int* orow = top + ((size_t)(b*S_ + s0 + w)) * TK_;
    for (int i = 0; i < 64; ++i) {
        const int t = i*64 + lane;
        const u32 key = fkey(srow[t]);
        const bool gt = key > T, eq = key == T;
        const u64 mgt = __ballot(gt), meq = __ballot(eq);
        if (gt) orow[cgt + __popcll(mgt & lmask)] = t;
        if (eq) {
            const int rk = ceq + __popcll(meq & lmask);
            if (rk < krem) orow[G + rk] = t;
        }
        cgt += __popcll(mgt); ceq += __popcll(meq);
    }
}

// ---------------- Kernel 3: gathered sparse attention ----------------
// One block per (b,s), 512 thr. K gathered to LDS (stride 68 to break banks),
// scores for all 8 heads, block softmax, single-pass PV (V read once from L2).
__global__ __launch_bounds__(512) void k_attn(
    const float* __restrict__ Q, const float* __restrict__ K,
    const float* __restrict__ V, const int* __restrict__ top,
    float* __restrict__ out)
{
    extern __shared__ float smem[];
    float* klds  = smem;                 // [256][68]
    float* qlds  = smem + 17408;         // [8][64]
    float* wl    = smem + 17920;         // [8][256]
    int*   il    = (int*)(smem + 19968); // [256]
    float* redm  = smem + 20224;         // [8][4]
    float* reds  = smem + 20256;         // [8][4]
    float* opart = smem + 20288;         // [32][8][64]

    const int tid = threadIdx.x;
    const int b   = blockIdx.x >> 12;
    const int s   = blockIdx.x & 4095;

    if (tid < 256) il[tid] = top[((size_t)(b*S_ + s))*TK_ + tid];
    {
        const int h = tid >> 6, c = tid & 63;
        qlds[tid] = Q[((size_t)(b*HQ_ + h))*S_*64 + (size_t)s*64 + c];
    }
    __syncthreads();

    #pragma unroll
    for (int itr = 0; itr < 8; ++itr) {
        const int chunk = tid + itr*512;
        const int row = chunk >> 4, e4 = (chunk & 15) << 2;
        const float4 kv = *(const float4*)&K[((size_t)(b*S_ + il[row]))*64 + e4];
        *(float4*)&klds[row*68 + e4] = kv;
    }
    __syncthreads();

    // ---- scores: thread (j = tid&255, hh = tid>>8) does heads hh*4..hh*4+3
    const int j  = tid & 255;
    const int hh = tid >> 8;
    float a4[4] = {0.f, 0.f, 0.f, 0.f};
    #pragma unroll
    for (int cb = 0; cb < 4; ++cb) {
        const float* kr = &klds[j*68 + cb*16];
        const float4 kk0 = *(const float4*)(kr);
        const float4 kk1 = *(const float4*)(kr+4);
        const float4 kk2 = *(const float4*)(kr+8);
        const float4 kk3 = *(const float4*)(kr+12);
        #pragma unroll
        for (int h4 = 0; h4 < 4; ++h4) {
            const float* qr = &qlds[(hh*4 + h4)*64 + cb*16];
            a4[h4] += dot4(kk0, *(const float4*)(qr))
                    + dot4(kk1, *(const float4*)(qr+4))
                    + dot4(kk2, *(const float4*)(qr+8))
                    + dot4(kk3, *(const float4*)(qr+12));
        }
    }
    #pragma unroll
    for (int h4 = 0; h4 < 4; ++h4) a4[h4] *= 0.125f;

    // ---- softmax ----
    const int lane = tid & 63, w = tid >> 6;
    #pragma unroll
    for (int h4 = 0; h4 < 4; ++h4) {
        float m = a4[h4];
        #pragma unroll
        for (int off = 32; off >= 1; off >>= 1) m = fmaxf(m, __shfl_xor(m, off, 64));
        if (lane == 0) redm[(hh*4 + h4)*4 + (w & 3)] = m;
    }
    __syncthreads();
    float ev[4];
    #pragma unroll
    for (int h4 = 0; h4 < 4; ++h4) {
        const int h = hh*4 + h4;
        const float m = fmaxf(fmaxf(redm[h*4+0], redm[h*4+1]),
                              fmaxf(redm[h*4+2], redm[h*4+3]));
        float e = expf(a4[h4] - m);
        ev[h4] = e;
        float ssum = e;
        #pragma unroll
        for (int off = 32; off >= 1; off >>= 1) ssum += __shfl_xor(ssum, off, 64);
        if (lane == 0) reds[h*4 + (w & 3)] = ssum;
    }
    __syncthreads();
    #pragma unroll
    for (int h4 = 0; h4 < 4; ++h4) wl[(hh*4 + h4)*256 + j] = ev[h4];
    __syncthreads();

    // ---- PV: thread (d-quad = tid&15, jg = tid>>4) reads V once ----
    const int d4 = (tid & 15) << 2;
    const int jg = tid >> 4;
    float4 p[8];
    #pragma unroll
    for (int h = 0; h < 8; ++h) { p[h].x = 0.f; p[h].y = 0.f; p[h].z = 0.f; p[h].w = 0.f; }
    #pragma unroll
    for (int i = 0; i < 8; ++i) {
        const int jj = jg*8 + i;
        const float4 v4 = *(const float4*)&V[((size_t)(b*S_ + il[jj]))*64 + d4];
        #pragma unroll
        for (int h = 0; h < 8; ++h) {
            const float wv = wl[h*256 + jj];
            p[h].x += wv * v4.x; p[h].y += wv * v4.y;
            p[h].z += wv * v4.z; p[h].w += wv * v4.w;
        }
    }
    #pragma unroll
    for (int h = 0; h < 8; ++h)
        *(float4*)&opart[(jg*8 + h)*64 + d4] = p[h];
    __syncthreads();

    // ---- final reduce + write ----
    {
        const int h = tid >> 6, d = tid & 63;
        float ss = 0.f;
        #pragma unroll
        for (int g2 = 0; g2 < 32; ++g2) ss += opart[(g2*8 + h)*64 + d];
        const float Z = reds[h*4+0] + reds[h*4+1] + reds[h*4+2] + reds[h*4+3];
        out[((size_t)(b*S_ + s))*512 + (size_t)h*64 + d] = ss / Z;
    }
}

// ---------------- launcher ----------------
extern "C" void kernel_launch(void* const* d_in, const int* in_sizes, int n_in,
                              void* d_out, int out_size, void* d_ws, size_t ws_size,
                              hipStream_t stream) {
    const float* x  = (const float*)d_in[0];
    const float* Q  = (const float*)d_in[1];
    const float* K  = (const float*)d_in[2];
    const float* V  = (const float*)d_in[3];
    const float* Wq = (const float*)d_in[4];
    const float* bq = (const float*)d_in[5];
    const float* Wk = (const float*)d_in[6];
    const float* bk = (const float*)d_in[7];
    const float* lg = (const float*)d_in[8];
    const float* lb = (const float*)d_in[9];
    const float* iw = (const float*)d_in[10];
    float* out = (float*)d_out;

    float* ws = (float*)d_ws;
    float* qi = ws;                    // [B*S, 64]
    float* ki = ws + (size_t)B_*S_*64; // [B*S, 64]
    int*  top = (int*)(ws + (size_t)2*B_*S_*64); // [B*S, 256]

    const int K2_LDS = (8*4096 + 8*64)*4 + 8*256*4 + 16*4;   // 141376 B
    const int K3_LDS = (20288 + 32*8*64)*4;                  // 146688 B
    static bool attr_done = false;
    hipFuncSetAttribute((const void*)k_score_topk,
                        hipFuncAttributeMaxDynamicSharedMemorySize, K2_LDS);
    hipFuncSetAttribute((const void*)k_attn,
                        hipFuncAttributeMaxDynamicSharedMemorySize, K3_LDS);
    (void)attr_done; (void)in_sizes; (void)n_in; (void)out_size; (void)ws_size;

    k_proj_ln<<<dim3((B_*S_)/16), dim3(256), 0, stream>>>(
        x, Wq, bq, Wk, bk, lg, lb, qi, ki);
    k_score_topk<<<dim3(B_*(S_/8)), dim3(512), K2_LDS, stream>>>(
        qi, ki, iw, top);
    k_attn<<<dim3(B_*S_), dim3(512), K3_LDS, stream>>>(
        Q, K, V, top, out);
}

// Round 3
// 713.319 us; speedup vs baseline: 1.5094x; 1.5094x over previous
//
#include <hip/hip_runtime.h>
#include <math.h>

// DSA sparse attention, MI355X. Round 3 = Round 2 resubmit (bench infra
// timeout, kernel never ran): restructured k2 (t-partitioned quadrant
// scores, q from L2, 2-sweep LDS keybuf, wave-parallel radix select) and
// slim k3 (regs-resident K gather, 19 KB LDS).

#define B_   2
#define S_   4096
#define DM_  1024
#define HQ_  8
#define TK_  256

typedef unsigned int u32;
typedef unsigned long long u64;

__device__ __forceinline__ float dot4(const float4 a, const float4 b) {
    return a.x*b.x + a.y*b.y + a.z*b.z + a.w*b.w;
}
// monotonic float->uint key
__device__ __forceinline__ u32 fkey(float f) {
    u32 b = __float_as_uint(f);
    return (b & 0x80000000u) ? ~b : (b | 0x80000000u);
}

// ---------------- Kernel 1: indexer projections + LayerNorm ----------------
__global__ __launch_bounds__(256) void k_proj_ln(
    const float* __restrict__ x,
    const float* __restrict__ Wq, const float* __restrict__ bq,
    const float* __restrict__ Wk, const float* __restrict__ bk,
    const float* __restrict__ lg, const float* __restrict__ lb,
    float* __restrict__ qi, float* __restrict__ ki)
{
    __shared__ float xs[16*64];
    const int tid = threadIdx.x;
    const int o   = tid & 63;
    const int rh  = tid >> 6;
    const size_t r0 = (size_t)blockIdx.x * 16;

    float acc[2][4];
    #pragma unroll
    for (int j = 0; j < 2; ++j)
        #pragma unroll
        for (int r = 0; r < 4; ++r) acc[j][r] = 0.f;

    const float* wqr = Wq + (size_t)o * DM_;
    const float* wkr = Wk + (size_t)o * DM_;

    for (int kt = 0; kt < 16; ++kt) {
        {
            const int row = tid >> 4, c4 = (tid & 15) << 2;
            *(float4*)&xs[row*64 + c4] =
                *(const float4*)&x[(r0 + row) * DM_ + kt*64 + c4];
        }
        __syncthreads();
        #pragma unroll
        for (int k8 = 0; k8 < 8; ++k8) {
            const int base = kt*64 + k8*8;
            const float4 wq0 = *(const float4*)&wqr[base];
            const float4 wq1 = *(const float4*)&wqr[base+4];
            const float4 wk0 = *(const float4*)&wkr[base];
            const float4 wk1 = *(const float4*)&wkr[base+4];
            #pragma unroll
            for (int rr = 0; rr < 4; ++rr) {
                const float* xr = &xs[(rh*4+rr)*64 + k8*8];
                const float4 xa = *(const float4*)xr;
                const float4 xb = *(const float4*)(xr+4);
                acc[0][rr] += dot4(wq0,xa) + dot4(wq1,xb);
                acc[1][rr] += dot4(wk0,xa) + dot4(wk1,xb);
            }
        }
        __syncthreads();
    }

    const float bqv = bq[o], bkv = bk[o];
    const float gv = lg[o & 31], bv = lb[o & 31];
    #pragma unroll
    for (int j = 0; j < 2; ++j) {
        #pragma unroll
        for (int rr = 0; rr < 4; ++rr) {
            float v = acc[j][rr] + (j == 0 ? bqv : bkv);
            float s = v;
            #pragma unroll
            for (int off = 16; off >= 1; off >>= 1) s += __shfl_xor(s, off, 32);
            const float m = s * (1.f/32.f);
            const float d = v - m;
            float s2 = d * d;
            #pragma unroll
            for (int off = 16; off >= 1; off >>= 1) s2 += __shfl_xor(s2, off, 32);
            const float var = s2 * (1.f/32.f);
            const float ov = d * rsqrtf(var + 1e-5f) * gv + bv;
            const size_t row = r0 + rh*4 + rr;
            if (j == 0) qi[row*64 + o] = ov;
            else        ki[row*64 + o] = ov;
        }
    }
}

// ---------------- Kernel 2: pairwise scores + exact top-256 ----------------
// 512 thr (8 waves), 8 selection-rows per block, two sweeps of 4 rows.
// Scores: waves partition t (wave w: t in [w*512,(w+1)*512)); each 4-lane
// quadrant group computes one t's 64-dim dot (16 dims/lane, combined via
// shfl_xor). q read from global (L2) once per t per sweep; k broadcast LDS.
// Keys (monotone u32) in LDS keybuf[4][4096]; exact 4x8-bit radix select
// with wave-parallel suffix scan; ties at threshold -> lowest index.
__global__ __launch_bounds__(512) void k_score_topk(
    const float* __restrict__ qi, const float* __restrict__ ki,
    const float* __restrict__ idxw, int* __restrict__ top)
{
    extern __shared__ u32 dynlds[];
    u32*   keybuf = dynlds;                 // [4][4096]
    float* kl     = (float*)(dynlds + 4*4096); // [8][64]
    u32*   hist   = dynlds + 4*4096 + 8*64;    // [4][256]

    const int tid  = threadIdx.x;
    const int w    = tid >> 6, lane = tid & 63;
    const int c    = lane & 3, tsub = lane >> 2;
    const int b    = blockIdx.x >> 9;
    const int s0   = (blockIdx.x & 511) << 3;
    const float w0 = idxw[0], w1 = idxw[1];

    kl[tid] = ki[((size_t)(b*S_ + s0 + (tid>>6)))*64 + (tid&63)];
    __syncthreads();

    const float* qbase = qi + ((size_t)b*S_)*64 + c*16;
    const int rsel  = w & 3;          // row this wave helps select
    const int ibase = (w >> 2) * 32;  // its half of the i-range

    #pragma unroll 1
    for (int half = 0; half < 2; ++half) {
        // ---- score sweep: 4 rows (half*4 .. half*4+3) over all t ----
        #pragma unroll 2
        for (int it = 0; it < 32; ++it) {
            const int t = (w << 9) + (it << 4) + tsub;
            const float* qr = qbase + (size_t)t*64;
            const float4 q0 = *(const float4*)(qr);
            const float4 q1 = *(const float4*)(qr+4);
            const float4 q2 = *(const float4*)(qr+8);
            const float4 q3 = *(const float4*)(qr+12);
            #pragma unroll
            for (int r = 0; r < 4; ++r) {
                const float* kr = &kl[(half*4 + r)*64 + c*16];
                float s = dot4(q0, *(const float4*)(kr))
                        + dot4(q1, *(const float4*)(kr+4))
                        + dot4(q2, *(const float4*)(kr+8))
                        + dot4(q3, *(const float4*)(kr+12));
                s += __shfl_xor(s, 1);
                const float o2 = __shfl_xor(s, 2);
                const float h0 = (c < 2) ? s : o2;
                const float h1 = (c < 2) ? o2 : s;
                const float scr = w0*fmaxf(h0, 0.f) + w1*fmaxf(h1, 0.f);
                if (c == 0) keybuf[r*4096 + t] = fkey(scr);
            }
        }

        // ---- radix select: waves w and w+4 cooperate on row rsel ----
        const u32* srow = keybuf + rsel*4096;
        u32* hw = hist + rsel*256;
        u32 prefix = 0; u32 krem = TK_;
        #pragma unroll 1
        for (int pass = 0; pass < 4; ++pass) {
            const int shift = 24 - 8*pass;
            __syncthreads();
            ((uint4*)hw)[lane] = make_uint4(0u,0u,0u,0u);
            __syncthreads();
            #pragma unroll
            for (int i2 = 0; i2 < 32; ++i2) {
                const u32 kk = srow[(ibase + i2)*64 + lane];
                const bool ok = (pass == 0) | ((kk >> (shift+8)) == prefix);
                if (ok) atomicAdd(&hw[(kk >> shift) & 255], 1u);
            }
            __syncthreads();
            const uint4 h4 = ((const uint4*)hw)[lane];
            const u32 vsum = h4.x + h4.y + h4.z + h4.w;
            u32 ssum = vsum;
            #pragma unroll
            for (int off = 1; off < 64; off <<= 1) {
                const u32 tt = __shfl_down(ssum, off);
                if (lane + off < 64) ssum += tt;
            }
            u32 up = __shfl_down(ssum, 1);
            if (lane == 63) up = 0;
            const u32 a3 = up;
            const u32 a2 = a3 + h4.w;
            const u32 a1 = a2 + h4.z;
            const u32 a0 = a1 + h4.y;
            u32 binl = 0, nkl = 0; bool hit = false;
            if      (a0 < krem && a0 + h4.x >= krem) { hit = true; binl = 4*lane+0; nkl = krem - a0; }
            else if (a1 < krem && a1 + h4.y >= krem) { hit = true; binl = 4*lane+1; nkl = krem - a1; }
            else if (a2 < krem && a2 + h4.z >= krem) { hit = true; binl = 4*lane+2; nkl = krem - a2; }
            else if (a3 < krem && a3 + h4.w >= krem) { hit = true; binl = 4*lane+3; nkl = krem - a3; }
            const u64 mball = __ballot(hit);
            const int src = __ffsll(mball) - 1;
            const u32 bsel = __shfl(binl, src);
            krem = __shfl(nkl, src);
            prefix = (prefix << 8) | bsel;
        }

        // ---- compaction (waves 0..3 only): > T all; == T lowest idx ----
        if (w < 4) {
            const u32 T = prefix;
            const int G = TK_ - (int)krem;
            const u64 lmask = (lane == 0) ? 0ull : ((~0ull) >> (64 - lane));
            int cgt = 0, ceq = 0;
            int* orow = top + ((size_t)(b*S_ + s0 + half*4 + w))*TK_;
            #pragma unroll
            for (int i = 0; i < 64; ++i) {
                const int t = i*64 + lane;
                const u32 kk = srow[i*64 + lane];
                const bool gt = kk > T, eq = kk == T;
                const u64 mgt = __ballot(gt), meq = __ballot(eq);
                if (gt) orow[cgt + __popcll(mgt & lmask)] = t;
                if (eq) {
                    const int rk = ceq + __popcll(meq & lmask);
                    if (rk < (int)krem) orow[G + rk] = t;
                }
                cgt += __popcll(mgt); ceq += __popcll(meq);
            }
        }
        __syncthreads();  // keybuf safe to overwrite next half
    }
}

// ---------------- Kernel 3: gathered sparse attention ----------------
// 256 thr (4 waves), one block per (b,s). K rows gathered into registers
// (thread j <-> candidate j), q broadcast from LDS; softmax via LDS
// transpose + wave reduce; PV gathers V from L2 with full line coverage,
// partial sums reduced via shfl_xor. ~19 KB LDS.
__global__ __launch_bounds__(256) void k_attn(
    const float* __restrict__ Q, const float* __restrict__ K,
    const float* __restrict__ V, const int* __restrict__ top,
    float* __restrict__ out)
{
    __shared__ int   il[256];
    __shared__ float qsm[8*64];
    __shared__ float wmat[8*256];
    __shared__ float opart[4*8*64];
    __shared__ float MZ[16];

    const int tid  = threadIdx.x;
    const int b    = blockIdx.x >> 12;
    const int s    = blockIdx.x & 4095;
    const int lane = tid & 63, w = tid >> 6;

    il[tid] = top[((size_t)(b*S_ + s))*TK_ + tid];
    qsm[tid]     = Q[((size_t)(b*HQ_ + (tid>>6)))*S_*64 + (size_t)s*64 + (tid&63)];
    qsm[256+tid] = Q[((size_t)(b*HQ_ + 4 + (tid>>6)))*S_*64 + (size_t)s*64 + (tid&63)];
    __syncthreads();

    // ---- scores: thread j = tid; K row in regs, q broadcast ----
    const float* kp = K + ((size_t)(b*S_ + il[tid]))*64;
    float4 kx[16];
    #pragma unroll
    for (int g = 0; g < 16; ++g) kx[g] = *(const float4*)(kp + g*4);
    float sc[8];
    #pragma unroll
    for (int h = 0; h < 8; ++h) {
        float a = 0.f;
        #pragma unroll
        for (int g = 0; g < 16; ++g)
            a += dot4(*(const float4*)&qsm[h*64 + g*4], kx[g]);
        sc[h] = a * 0.125f;
    }
    #pragma unroll
    for (int h = 0; h < 8; ++h) wmat[h*256 + tid] = sc[h];
    __syncthreads();

    // ---- per-head max (wave w: heads w, w+4) ----
    #pragma unroll
    for (int hh = 0; hh < 2; ++hh) {
        const int h = hh*4 + w;
        const float4 v4 = *(const float4*)&wmat[h*256 + lane*4];
        float mm = fmaxf(fmaxf(v4.x, v4.y), fmaxf(v4.z, v4.w));
        #pragma unroll
        for (int off = 32; off >= 1; off >>= 1) mm = fmaxf(mm, __shfl_xor(mm, off));
        if (lane == 0) MZ[h] = mm;
    }
    __syncthreads();
    #pragma unroll
    for (int h = 0; h < 8; ++h) wmat[h*256 + tid] = __expf(sc[h] - MZ[h]);
    __syncthreads();
    // ---- per-head sum ----
    #pragma unroll
    for (int hh = 0; hh < 2; ++hh) {
        const int h = hh*4 + w;
        const float4 v4 = *(const float4*)&wmat[h*256 + lane*4];
        float ss = v4.x + v4.y + v4.z + v4.w;
        #pragma unroll
        for (int off = 32; off >= 1; off >>= 1) ss += __shfl_xor(ss, off);
        if (lane == 0) MZ[8 + h] = ss;
    }
    __syncthreads();

    // ---- PV: lane = (jsub<<4)|dq; thread sums 16 j's, reduce via shfl ----
    const int dq = lane & 15, jsub = lane >> 4;
    float4 p[8];
    #pragma unroll
    for (int h = 0; h < 8; ++h) p[h] = make_float4(0.f,0.f,0.f,0.f);
    #pragma unroll
    for (int i = 0; i < 16; ++i) {
        const int j = w*64 + jsub*16 + i;
        const float4 v4 = *(const float4*)&V[((size_t)(b*S_ + il[j]))*64 + dq*4];
        #pragma unroll
        for (int h = 0; h < 8; ++h) {
            const float wv = wmat[h*256 + j];
            p[h].x += wv*v4.x; p[h].y += wv*v4.y;
            p[h].z += wv*v4.z; p[h].w += wv*v4.w;
        }
    }
    #pragma unroll
    for (int h = 0; h < 8; ++h) {
        p[h].x += __shfl_xor(p[h].x, 16); p[h].y += __shfl_xor(p[h].y, 16);
        p[h].z += __shfl_xor(p[h].z, 16); p[h].w += __shfl_xor(p[h].w, 16);
        p[h].x += __shfl_xor(p[h].x, 32); p[h].y += __shfl_xor(p[h].y, 32);
        p[h].z += __shfl_xor(p[h].z, 32); p[h].w += __shfl_xor(p[h].w, 32);
    }
    if (jsub == 0) {
        #pragma unroll
        for (int h = 0; h < 8; ++h)
            *(float4*)&opart[(w*8 + h)*64 + dq*4] = p[h];
    }
    __syncthreads();
    {
        const int h = tid >> 5, d0 = (tid & 31) * 2;
        float o0 = 0.f, o1 = 0.f;
        #pragma unroll
        for (int g = 0; g < 4; ++g) {
            o0 += opart[(g*8 + h)*64 + d0];
            o1 += opart[(g*8 + h)*64 + d0 + 1];
        }
        const float iz = 1.f / MZ[8 + h];
        *(float2*)&out[((size_t)(b*S_ + s))*512 + h*64 + d0] =
            make_float2(o0*iz, o1*iz);
    }
}

// ---------------- launcher ----------------
extern "C" void kernel_launch(void* const* d_in, const int* in_sizes, int n_in,
                              void* d_out, int out_size, void* d_ws, size_t ws_size,
                              hipStream_t stream) {
    const float* x  = (const float*)d_in[0];
    const float* Q  = (const float*)d_in[1];
    const float* K  = (const float*)d_in[2];
    const float* V  = (const float*)d_in[3];
    const float* Wq = (const float*)d_in[4];
    const float* bq = (const float*)d_in[5];
    const float* Wk = (const float*)d_in[6];
    const float* bk = (const float*)d_in[7];
    const float* lg = (const float*)d_in[8];
    const float* lb = (const float*)d_in[9];
    const float* iw = (const float*)d_in[10];
    float* out = (float*)d_out;

    float* ws = (float*)d_ws;
    float* qi = ws;                    // [B*S, 64]
    float* ki = ws + (size_t)B_*S_*64; // [B*S, 64]
    int*  top = (int*)(ws + (size_t)2*B_*S_*64); // [B*S, 256]

    const int K2_LDS = (4*4096 + 8*64 + 4*256) * 4; // 71680 B
    hipFuncSetAttribute((const void*)k_score_topk,
                        hipFuncAttributeMaxDynamicSharedMemorySize, K2_LDS);
    (void)in_sizes; (void)n_in; (void)out_size; (void)ws_size;

    k_proj_ln<<<dim3((B_*S_)/16), dim3(256), 0, stream>>>(
        x, Wq, bq, Wk, bk, lg, lb, qi, ki);
    k_score_topk<<<dim3(B_*(S_/8)), dim3(512), K2_LDS, stream>>>(
        qi, ki, iw, top);
    k_attn<<<dim3(B_*S_), dim3(256), 0, stream>>>(
        Q, K, V, top, out);
}

// Round 4
// 656.463 us; speedup vs baseline: 1.6401x; 1.0866x over previous
//
#include <hip/hip_runtime.h>
#include <math.h>

// DSA sparse attention, MI355X. Round 4: k2 split into k_scores (fp32 score
// GEMM -> global u32 keys, scalar-broadcast k, q in regs) + k_select
// (per-row exact 4x8-bit radix top-256 from LDS-staged keys). Old fused
// kernel kept as fallback if ws_size < 146 MB.

#define B_   2
#define S_   4096
#define DM_  1024
#define HQ_  8
#define TK_  256

typedef unsigned int u32;
typedef unsigned long long u64;

__device__ __forceinline__ float dot4(const float4 a, const float4 b) {
    return a.x*b.x + a.y*b.y + a.z*b.z + a.w*b.w;
}
// monotonic float->uint key
__device__ __forceinline__ u32 fkey(float f) {
    u32 b = __float_as_uint(f);
    return (b & 0x80000000u) ? ~b : (b | 0x80000000u);
}

// ---------------- Kernel 1: indexer projections + LayerNorm ----------------
__global__ __launch_bounds__(256) void k_proj_ln(
    const float* __restrict__ x,
    const float* __restrict__ Wq, const float* __restrict__ bq,
    const float* __restrict__ Wk, const float* __restrict__ bk,
    const float* __restrict__ lg, const float* __restrict__ lb,
    float* __restrict__ qi, float* __restrict__ ki)
{
    __shared__ float xs[16*64];
    const int tid = threadIdx.x;
    const int o   = tid & 63;
    const int rh  = tid >> 6;
    const size_t r0 = (size_t)blockIdx.x * 16;

    float acc[2][4];
    #pragma unroll
    for (int j = 0; j < 2; ++j)
        #pragma unroll
        for (int r = 0; r < 4; ++r) acc[j][r] = 0.f;

    const float* wqr = Wq + (size_t)o * DM_;
    const float* wkr = Wk + (size_t)o * DM_;

    for (int kt = 0; kt < 16; ++kt) {
        {
            const int row = tid >> 4, c4 = (tid & 15) << 2;
            *(float4*)&xs[row*64 + c4] =
                *(const float4*)&x[(r0 + row) * DM_ + kt*64 + c4];
        }
        __syncthreads();
        #pragma unroll
        for (int k8 = 0; k8 < 8; ++k8) {
            const int base = kt*64 + k8*8;
            const float4 wq0 = *(const float4*)&wqr[base];
            const float4 wq1 = *(const float4*)&wqr[base+4];
            const float4 wk0 = *(const float4*)&wkr[base];
            const float4 wk1 = *(const float4*)&wkr[base+4];
            #pragma unroll
            for (int rr = 0; rr < 4; ++rr) {
                const float* xr = &xs[(rh*4+rr)*64 + k8*8];
                const float4 xa = *(const float4*)xr;
                const float4 xb = *(const float4*)(xr+4);
                acc[0][rr] += dot4(wq0,xa) + dot4(wq1,xb);
                acc[1][rr] += dot4(wk0,xa) + dot4(wk1,xb);
            }
        }
        __syncthreads();
    }

    const float bqv = bq[o], bkv = bk[o];
    const float gv = lg[o & 31], bv = lb[o & 31];
    #pragma unroll
    for (int j = 0; j < 2; ++j) {
        #pragma unroll
        for (int rr = 0; rr < 4; ++rr) {
            float v = acc[j][rr] + (j == 0 ? bqv : bkv);
            float s = v;
            #pragma unroll
            for (int off = 16; off >= 1; off >>= 1) s += __shfl_xor(s, off, 32);
            const float m = s * (1.f/32.f);
            const float d = v - m;
            float s2 = d * d;
            #pragma unroll
            for (int off = 16; off >= 1; off >>= 1) s2 += __shfl_xor(s2, off, 32);
            const float var = s2 * (1.f/32.f);
            const float ov = d * rsqrtf(var + 1e-5f) * gv + bv;
            const size_t row = r0 + rh*4 + rr;
            if (j == 0) qi[row*64 + o] = ov;
            else        ki[row*64 + o] = ov;
        }
    }
}

// ---------------- Kernel 2a: score GEMM -> global keys ----------------
// Block 256 thr: 32 s-rows x 256 t-cols. Thread owns col t (q row in 64
// VGPRs); k values are wave-uniform scalar loads (SGPR operands). Writes
// monotone u32 keys, coalesced, [b][s][t] layout.
__global__ __launch_bounds__(256) void k_scores(
    const float* __restrict__ qi, const float* __restrict__ ki,
    const float* __restrict__ idxw, u32* __restrict__ keys)
{
    const int tid = threadIdx.x;
    const int ct  = blockIdx.x;            // 0..15 (t-tile)
    const int rt  = blockIdx.y;            // 0..255 (s-tile over both b)
    const int b   = rt >> 7;
    const int s0  = (rt & 127) * 32;
    const int t   = ct*256 + tid;

    // q row -> regs
    float q[64];
    {
        const float* qr = qi + ((size_t)(b*S_ + t))*64;
        #pragma unroll
        for (int g = 0; g < 16; ++g)
            *(float4*)&q[g*4] = *(const float4*)&qr[g*4];
    }
    const float w0 = idxw[0], w1 = idxw[1];
    const float* kb = ki + ((size_t)(b*S_ + s0))*64;
    u32* krow = keys + ((size_t)b*S_ + s0)*S_ + (size_t)ct*256 + tid;

    #pragma unroll 2
    for (int r = 0; r < 32; ++r) {
        const float* kr = kb + r*64;   // wave-uniform -> scalar loads
        float a0 = 0.f, a1 = 0.f;
        #pragma unroll
        for (int d = 0; d < 32; ++d) a0 = fmaf(kr[d],      q[d],      a0);
        #pragma unroll
        for (int d = 0; d < 32; ++d) a1 = fmaf(kr[32 + d], q[32 + d], a1);
        const float scr = w0*fmaxf(a0, 0.f) + w1*fmaxf(a1, 0.f);
        krow[(size_t)r*S_] = fkey(scr);
    }
}

// ---------------- Kernel 2b: exact top-256 per row ----------------
// One block (256 thr, 4 waves) per selection row. Keys staged in LDS,
// 4x8-bit radix (all waves feed histogram; redundant wave scan), two-phase
// ballot compaction; ties at threshold -> lowest index.
__global__ __launch_bounds__(256) void k_select(
    const u32* __restrict__ keys, int* __restrict__ top)
{
    __shared__ u32 kly[4096];
    __shared__ u32 hist[256];
    __shared__ u32 wcnt[8];

    const int tid = threadIdx.x, lane = tid & 63, w = tid >> 6;
    const size_t row = blockIdx.x;
    const u32* krow = keys + row * S_;

    #pragma unroll
    for (int i = 0; i < 4; ++i)
        ((uint4*)kly)[tid + i*256] = ((const uint4*)krow)[tid + i*256];
    __syncthreads();

    u32 prefix = 0; u32 krem = TK_;
    #pragma unroll 1
    for (int pass = 0; pass < 4; ++pass) {
        const int shift = 24 - 8*pass;
        if (tid < 64) ((uint4*)hist)[tid] = make_uint4(0u,0u,0u,0u);
        __syncthreads();
        #pragma unroll
        for (int i = 0; i < 16; ++i) {
            const u32 kk = kly[tid + i*256];
            const bool ok = (pass == 0) | ((kk >> (shift+8)) == prefix);
            if (ok) atomicAdd(&hist[(kk >> shift) & 255], 1u);
        }
        __syncthreads();
        const uint4 h4 = ((const uint4*)hist)[lane];
        u32 ssum = h4.x + h4.y + h4.z + h4.w;
        #pragma unroll
        for (int off = 1; off < 64; off <<= 1) {
            const u32 tt = __shfl_down(ssum, off);
            if (lane + off < 64) ssum += tt;
        }
        u32 up = __shfl_down(ssum, 1);
        if (lane == 63) up = 0;
        const u32 a3 = up;
        const u32 a2 = a3 + h4.w;
        const u32 a1 = a2 + h4.z;
        const u32 a0 = a1 + h4.y;
        u32 binl = 0, nkl = 0; bool hit = false;
        if      (a0 < krem && a0 + h4.x >= krem) { hit = true; binl = 4*lane+0; nkl = krem - a0; }
        else if (a1 < krem && a1 + h4.y >= krem) { hit = true; binl = 4*lane+1; nkl = krem - a1; }
        else if (a2 < krem && a2 + h4.z >= krem) { hit = true; binl = 4*lane+2; nkl = krem - a2; }
        else if (a3 < krem && a3 + h4.w >= krem) { hit = true; binl = 4*lane+3; nkl = krem - a3; }
        const u64 mball = __ballot(hit);
        const int src = __ffsll(mball) - 1;
        const u32 bsel = __shfl(binl, src);
        krem = __shfl(nkl, src);
        prefix = (prefix << 8) | bsel;
        __syncthreads();   // all waves done reading hist before next clear
    }

    // ---- compaction ----
    const u32 T = prefix;
    const int G = TK_ - (int)krem;
    const u64 lmask = (lane == 0) ? 0ull : ((~0ull) >> (64 - lane));
    int cgt = 0, ceq = 0;
    #pragma unroll
    for (int i = 0; i < 16; ++i) {
        const u32 kk = kly[w*1024 + i*64 + lane];
        cgt += __popcll(__ballot(kk > T));
        ceq += __popcll(__ballot(kk == T));
    }
    if (lane == 0) { wcnt[w] = (u32)cgt; wcnt[4 + w] = (u32)ceq; }
    __syncthreads();
    int gts = 0, eqs = 0;
    for (int w2 = 0; w2 < 4; ++w2) {
        if (w2 < w) { gts += (int)wcnt[w2]; eqs += (int)wcnt[4 + w2]; }
    }
    int* orow = top + row * TK_;
    cgt = gts; ceq = eqs;
    #pragma unroll
    for (int i = 0; i < 16; ++i) {
        const int idx = w*1024 + i*64 + lane;
        const u32 kk = kly[idx];
        const bool gt = kk > T, eq = kk == T;
        const u64 mgt = __ballot(gt), meq = __ballot(eq);
        if (gt) orow[cgt + __popcll(mgt & lmask)] = idx;
        if (eq) {
            const int rk = ceq + __popcll(meq & lmask);
            if (rk < (int)krem) orow[G + rk] = idx;
        }
        cgt += __popcll(mgt); ceq += __popcll(meq);
    }
}

// ---------------- Fallback fused kernel (round-3 k2) ----------------
__global__ __launch_bounds__(512) void k_score_topk(
    const float* __restrict__ qi, const float* __restrict__ ki,
    const float* __restrict__ idxw, int* __restrict__ top)
{
    extern __shared__ u32 dynlds[];
    u32*   keybuf = dynlds;                    // [4][4096]
    float* kl     = (float*)(dynlds + 4*4096); // [8][64]
    u32*   hist   = dynlds + 4*4096 + 8*64;    // [4][256]

    const int tid  = threadIdx.x;
    const int w    = tid >> 6, lane = tid & 63;
    const int c    = lane & 3, tsub = lane >> 2;
    const int b    = blockIdx.x >> 9;
    const int s0   = (blockIdx.x & 511) << 3;
    const float w0 = idxw[0], w1 = idxw[1];

    kl[tid] = ki[((size_t)(b*S_ + s0 + (tid>>6)))*64 + (tid&63)];
    __syncthreads();

    const float* qbase = qi + ((size_t)b*S_)*64 + c*16;
    const int rsel  = w & 3;
    const int ibase = (w >> 2) * 32;

    #pragma unroll 1
    for (int half = 0; half < 2; ++half) {
        #pragma unroll 2
        for (int it = 0; it < 32; ++it) {
            const int t = (w << 9) + (it << 4) + tsub;
            const float* qr = qbase + (size_t)t*64;
            const float4 q0 = *(const float4*)(qr);
            const float4 q1 = *(const float4*)(qr+4);
            const float4 q2 = *(const float4*)(qr+8);
            const float4 q3 = *(const float4*)(qr+12);
            #pragma unroll
            for (int r = 0; r < 4; ++r) {
                const float* kr = &kl[(half*4 + r)*64 + c*16];
                float s = dot4(q0, *(const float4*)(kr))
                        + dot4(q1, *(const float4*)(kr+4))
                        + dot4(q2, *(const float4*)(kr+8))
                        + dot4(q3, *(const float4*)(kr+12));
                s += __shfl_xor(s, 1);
                const float o2 = __shfl_xor(s, 2);
                const float h0 = (c < 2) ? s : o2;
                const float h1 = (c < 2) ? o2 : s;
                const float scr = w0*fmaxf(h0, 0.f) + w1*fmaxf(h1, 0.f);
                if (c == 0) keybuf[r*4096 + t] = fkey(scr);
            }
        }

        const u32* srow = keybuf + rsel*4096;
        u32* hw = hist + rsel*256;
        u32 prefix = 0; u32 krem = TK_;
        #pragma unroll 1
        for (int pass = 0; pass < 4; ++pass) {
            const int shift = 24 - 8*pass;
            __syncthreads();
            ((uint4*)hw)[lane] = make_uint4(0u,0u,0u,0u);
            __syncthreads();
            #pragma unroll
            for (int i2 = 0; i2 < 32; ++i2) {
                const u32 kk = srow[(ibase + i2)*64 + lane];
                const bool ok = (pass == 0) | ((kk >> (shift+8)) == prefix);
                if (ok) atomicAdd(&hw[(kk >> shift) & 255], 1u);
            }
            __syncthreads();
            const uint4 h4 = ((const uint4*)hw)[lane];
            u32 ssum = h4.x + h4.y + h4.z + h4.w;
            #pragma unroll
            for (int off = 1; off < 64; off <<= 1) {
                const u32 tt = __shfl_down(ssum, off);
                if (lane + off < 64) ssum += tt;
            }
            u32 up = __shfl_down(ssum, 1);
            if (lane == 63) up = 0;
            const u32 a3 = up;
            const u32 a2 = a3 + h4.w;
            const u32 a1 = a2 + h4.z;
            const u32 a0 = a1 + h4.y;
            u32 binl = 0, nkl = 0; bool hit = false;
            if      (a0 < krem && a0 + h4.x >= krem) { hit = true; binl = 4*lane+0; nkl = krem - a0; }
            else if (a1 < krem && a1 + h4.y >= krem) { hit = true; binl = 4*lane+1; nkl = krem - a1; }
            else if (a2 < krem && a2 + h4.z >= krem) { hit = true; binl = 4*lane+2; nkl = krem - a2; }
            else if (a3 < krem && a3 + h4.w >= krem) { hit = true; binl = 4*lane+3; nkl = krem - a3; }
            const u64 mball = __ballot(hit);
            const int src = __ffsll(mball) - 1;
            const u32 bsel = __shfl(binl, src);
            krem = __shfl(nkl, src);
            prefix = (prefix << 8) | bsel;
        }

        if (w < 4) {
            const u32 T = prefix;
            const int G = TK_ - (int)krem;
            const u64 lmask = (lane == 0) ? 0ull : ((~0ull) >> (64 - lane));
            int cgt = 0, ceq = 0;
            int* orow = top + ((size_t)(b*S_ + s0 + half*4 + w))*TK_;
            #pragma unroll
            for (int i = 0; i < 64; ++i) {
                const int t = i*64 + lane;
                const u32 kk = srow[i*64 + lane];
                const bool gt = kk > T, eq = kk == T;
                const u64 mgt = __ballot(gt), meq = __ballot(eq);
                if (gt) orow[cgt + __popcll(mgt & lmask)] = t;
                if (eq) {
                    const int rk = ceq + __popcll(meq & lmask);
                    if (rk < (int)krem) orow[G + rk] = t;
                }
                cgt += __popcll(mgt); ceq += __popcll(meq);
            }
        }
        __syncthreads();
    }
}

// ---------------- Kernel 3: gathered sparse attention ----------------
__global__ __launch_bounds__(256) void k_attn(
    const float* __restrict__ Q, const float* __restrict__ K,
    const float* __restrict__ V, const int* __restrict__ top,
    float* __restrict__ out)
{
    __shared__ int   il[256];
    __shared__ float qsm[8*64];
    __shared__ float wmat[8*256];
    __shared__ float opart[4*8*64];
    __shared__ float MZ[16];

    const int tid  = threadIdx.x;
    const int b    = blockIdx.x >> 12;
    const int s    = blockIdx.x & 4095;
    const int lane = tid & 63, w = tid >> 6;

    il[tid] = top[((size_t)(b*S_ + s))*TK_ + tid];
    qsm[tid]     = Q[((size_t)(b*HQ_ + (tid>>6)))*S_*64 + (size_t)s*64 + (tid&63)];
    qsm[256+tid] = Q[((size_t)(b*HQ_ + 4 + (tid>>6)))*S_*64 + (size_t)s*64 + (tid&63)];
    __syncthreads();

    const float* kp = K + ((size_t)(b*S_ + il[tid]))*64;
    float4 kx[16];
    #pragma unroll
    for (int g = 0; g < 16; ++g) kx[g] = *(const float4*)(kp + g*4);
    float sc[8];
    #pragma unroll
    for (int h = 0; h < 8; ++h) {
        float a = 0.f;
        #pragma unroll
        for (int g = 0; g < 16; ++g)
            a += dot4(*(const float4*)&qsm[h*64 + g*4], kx[g]);
        sc[h] = a * 0.125f;
    }
    #pragma unroll
    for (int h = 0; h < 8; ++h) wmat[h*256 + tid] = sc[h];
    __syncthreads();

    #pragma unroll
    for (int hh = 0; hh < 2; ++hh) {
        const int h = hh*4 + w;
        const float4 v4 = *(const float4*)&wmat[h*256 + lane*4];
        float mm = fmaxf(fmaxf(v4.x, v4.y), fmaxf(v4.z, v4.w));
        #pragma unroll
        for (int off = 32; off >= 1; off >>= 1) mm = fmaxf(mm, __shfl_xor(mm, off));
        if (lane == 0) MZ[h] = mm;
    }
    __syncthreads();
    #pragma unroll
    for (int h = 0; h < 8; ++h) wmat[h*256 + tid] = __expf(sc[h] - MZ[h]);
    __syncthreads();
    #pragma unroll
    for (int hh = 0; hh < 2; ++hh) {
        const int h = hh*4 + w;
        const float4 v4 = *(const float4*)&wmat[h*256 + lane*4];
        float ss = v4.x + v4.y + v4.z + v4.w;
        #pragma unroll
        for (int off = 32; off >= 1; off >>= 1) ss += __shfl_xor(ss, off);
        if (lane == 0) MZ[8 + h] = ss;
    }
    __syncthreads();

    const int dq = lane & 15, jsub = lane >> 4;
    float4 p[8];
    #pragma unroll
    for (int h = 0; h < 8; ++h) p[h] = make_float4(0.f,0.f,0.f,0.f);
    #pragma unroll
    for (int i = 0; i < 16; ++i) {
        const int j = w*64 + jsub*16 + i;
        const float4 v4 = *(const float4*)&V[((size_t)(b*S_ + il[j]))*64 + dq*4];
        #pragma unroll
        for (int h = 0; h < 8; ++h) {
            const float wv = wmat[h*256 + j];
            p[h].x += wv*v4.x; p[h].y += wv*v4.y;
            p[h].z += wv*v4.z; p[h].w += wv*v4.w;
        }
    }
    #pragma unroll
    for (int h = 0; h < 8; ++h) {
        p[h].x += __shfl_xor(p[h].x, 16); p[h].y += __shfl_xor(p[h].y, 16);
        p[h].z += __shfl_xor(p[h].z, 16); p[h].w += __shfl_xor(p[h].w, 16);
        p[h].x += __shfl_xor(p[h].x, 32); p[h].y += __shfl_xor(p[h].y, 32);
        p[h].z += __shfl_xor(p[h].z, 32); p[h].w += __shfl_xor(p[h].w, 32);
    }
    if (jsub == 0) {
        #pragma unroll
        for (int h = 0; h < 8; ++h)
            *(float4*)&opart[(w*8 + h)*64 + dq*4] = p[h];
    }
    __syncthreads();
    {
        const int h = tid >> 5, d0 = (tid & 31) * 2;
        float o0 = 0.f, o1 = 0.f;
        #pragma unroll
        for (int g = 0; g < 4; ++g) {
            o0 += opart[(g*8 + h)*64 + d0];
            o1 += opart[(g*8 + h)*64 + d0 + 1];
        }
        const float iz = 1.f / MZ[8 + h];
        *(float2*)&out[((size_t)(b*S_ + s))*512 + h*64 + d0] =
            make_float2(o0*iz, o1*iz);
    }
}

// ---------------- launcher ----------------
extern "C" void kernel_launch(void* const* d_in, const int* in_sizes, int n_in,
                              void* d_out, int out_size, void* d_ws, size_t ws_size,
                              hipStream_t stream) {
    const float* x  = (const float*)d_in[0];
    const float* Q  = (const float*)d_in[1];
    const float* K  = (const float*)d_in[2];
    const float* V  = (const float*)d_in[3];
    const float* Wq = (const float*)d_in[4];
    const float* bq = (const float*)d_in[5];
    const float* Wk = (const float*)d_in[6];
    const float* bk = (const float*)d_in[7];
    const float* lg = (const float*)d_in[8];
    const float* lb = (const float*)d_in[9];
    const float* iw = (const float*)d_in[10];
    float* out = (float*)d_out;

    char* ws = (char*)d_ws;
    float* qi = (float*)ws;                         // 2 MB
    float* ki = (float*)(ws + (2u<<20));            // 2 MB
    int*  top = (int*)(ws + (4u<<20));              // 8 MB
    u32* keys = (u32*)(ws + (16u<<20));             // 128 MB
    const size_t need = (16u<<20) + sizeof(u32)*(size_t)B_*S_*S_;

    (void)in_sizes; (void)n_in; (void)out_size;

    k_proj_ln<<<dim3((B_*S_)/16), dim3(256), 0, stream>>>(
        x, Wq, bq, Wk, bk, lg, lb, qi, ki);

    if (ws_size >= need) {
        k_scores<<<dim3(S_/256, (B_*S_)/32), dim3(256), 0, stream>>>(
            qi, ki, iw, keys);
        k_select<<<dim3(B_*S_), dim3(256), 0, stream>>>(keys, top);
    } else {
        const int K2_LDS = (4*4096 + 8*64 + 4*256) * 4; // 71680 B
        hipFuncSetAttribute((const void*)k_score_topk,
                            hipFuncAttributeMaxDynamicSharedMemorySize, K2_LDS);
        k_score_topk<<<dim3(B_*(S_/8)), dim3(512), K2_LDS, stream>>>(
            qi, ki, iw, top);
    }

    k_attn<<<dim3(B_*S_), dim3(256), 0, stream>>>(
        Q, K, V, top, out);
}

// Round 5
// 540.125 us; speedup vs baseline: 1.9934x; 1.2154x over previous
//
#include <hip/hip_runtime.h>
#include <math.h>

// DSA sparse attention, MI355X. Round 5: MFMA score GEMM via exact 3-limb
// bf16 decomposition (v = a+b+c exactly; 6 products/head -> rel err ~2^-25,
// below fp32 noise) + per-wave histograms in k_select.

#define B_   2
#define S_   4096
#define DM_  1024
#define HQ_  8
#define TK_  256

typedef unsigned int u32;
typedef unsigned long long u64;
typedef unsigned short US;
typedef __attribute__((ext_vector_type(8))) short short8;
typedef __attribute__((ext_vector_type(4))) float f32x4;

__device__ __forceinline__ float dot4(const float4 a, const float4 b) {
    return a.x*b.x + a.y*b.y + a.z*b.z + a.w*b.w;
}
// monotonic float->uint key
__device__ __forceinline__ u32 fkey(float f) {
    u32 b = __float_as_uint(f);
    return (b & 0x80000000u) ? ~b : (b | 0x80000000u);
}
// RNE round-to-bf16 helpers (bit-level; NaN not possible here)
__device__ __forceinline__ u32 bfbits(float f) {
    const u32 u = __float_as_uint(f);
    return (u + 0x7FFFu + ((u >> 16) & 1u)) >> 16;
}
__device__ __forceinline__ float bfval(u32 bits) {
    return __uint_as_float(bits << 16);
}

// ---------------- Kernel 1: indexer projections + LayerNorm + limb split ----
// Emits 3-limb bf16 decompositions of q_i and k_i: v = a + b + c EXACTLY
// (each RNE bf16 peels >=8 mantissa bits; fp32 has 24).
__global__ __launch_bounds__(256) void k_proj_ln(
    const float* __restrict__ x,
    const float* __restrict__ Wq, const float* __restrict__ bq,
    const float* __restrict__ Wk, const float* __restrict__ bk,
    const float* __restrict__ lg, const float* __restrict__ lb,
    US* __restrict__ qa, US* __restrict__ qb, US* __restrict__ qc,
    US* __restrict__ ka, US* __restrict__ kb, US* __restrict__ kc)
{
    __shared__ float xs[16*64];
    const int tid = threadIdx.x;
    const int o   = tid & 63;
    const int rh  = tid >> 6;
    const size_t r0 = (size_t)blockIdx.x * 16;

    float acc[2][4];
    #pragma unroll
    for (int j = 0; j < 2; ++j)
        #pragma unroll
        for (int r = 0; r < 4; ++r) acc[j][r] = 0.f;

    const float* wqr = Wq + (size_t)o * DM_;
    const float* wkr = Wk + (size_t)o * DM_;

    for (int kt = 0; kt < 16; ++kt) {
        {
            const int row = tid >> 4, c4 = (tid & 15) << 2;
            *(float4*)&xs[row*64 + c4] =
                *(const float4*)&x[(r0 + row) * DM_ + kt*64 + c4];
        }
        __syncthreads();
        #pragma unroll
        for (int k8 = 0; k8 < 8; ++k8) {
            const int base = kt*64 + k8*8;
            const float4 wq0 = *(const float4*)&wqr[base];
            const float4 wq1 = *(const float4*)&wqr[base+4];
            const float4 wk0 = *(const float4*)&wkr[base];
            const float4 wk1 = *(const float4*)&wkr[base+4];
            #pragma unroll
            for (int rr = 0; rr < 4; ++rr) {
                const float* xr = &xs[(rh*4+rr)*64 + k8*8];
                const float4 xa = *(const float4*)xr;
                const float4 xb = *(const float4*)(xr+4);
                acc[0][rr] += dot4(wq0,xa) + dot4(wq1,xb);
                acc[1][rr] += dot4(wk0,xa) + dot4(wk1,xb);
            }
        }
        __syncthreads();
    }

    const float bqv = bq[o], bkv = bk[o];
    const float gv = lg[o & 31], bv = lb[o & 31];
    #pragma unroll
    for (int j = 0; j < 2; ++j) {
        #pragma unroll
        for (int rr = 0; rr < 4; ++rr) {
            float v = acc[j][rr] + (j == 0 ? bqv : bkv);
            float s = v;
            #pragma unroll
            for (int off = 16; off >= 1; off >>= 1) s += __shfl_xor(s, off, 32);
            const float m = s * (1.f/32.f);
            const float d = v - m;
            float s2 = d * d;
            #pragma unroll
            for (int off = 16; off >= 1; off >>= 1) s2 += __shfl_xor(s2, off, 32);
            const float var = s2 * (1.f/32.f);
            const float ov = d * rsqrtf(var + 1e-5f) * gv + bv;
            const size_t idx = (r0 + rh*4 + rr)*64 + o;
            const u32 ab = bfbits(ov);
            const float fa = bfval(ab);
            const float r1 = ov - fa;          // exact
            const u32 bb = bfbits(r1);
            const float fb = bfval(bb);
            const u32 cb = bfbits(r1 - fb);    // r1-fb exact, fits bf16
            if (j == 0) { qa[idx] = (US)ab; qb[idx] = (US)bb; qc[idx] = (US)cb; }
            else        { ka[idx] = (US)ab; kb[idx] = (US)bb; kc[idx] = (US)cb; }
        }
    }
}

// ---------------- Kernel 2a: MFMA score GEMM -> global keys ----------------
// Block 256 thr = 4 waves in 2x2; block tile 64(s) x 64(t); wave tile 32x32.
// Per 16x16 C tile, per head: 6 MFMAs (aa',ab',ba',ac',ca',bb') accumulate
// the exact-split product to ~2^-25 rel error. relu per head, weighted sum,
// monotone key, store. A = k_i (M=s), B = q_i (N=t), K=32 feature dims.
// Frag layout (16x16x32): A row = lane&15, k = (lane>>4)*8 + e;
// B col = lane&15, same k. C: col = lane&15, row = (lane>>4)*4 + reg.
__global__ __launch_bounds__(256) void k_scores_mfma(
    const US* __restrict__ qa, const US* __restrict__ qb, const US* __restrict__ qc,
    const US* __restrict__ ka, const US* __restrict__ kb, const US* __restrict__ kc,
    const float* __restrict__ idxw, u32* __restrict__ keys)
{
    const int tid  = threadIdx.x;
    const int w    = tid >> 6, lane = tid & 63;
    const int row16 = lane & 15, kblk = lane >> 4;
    const int b    = blockIdx.y >> 6;
    const int sB   = (blockIdx.y & 63)*64 + (w >> 1)*32;
    const int tB   = blockIdx.x*64 + (w & 1)*32;
    const float w0 = idxw[0], w1 = idxw[1];

    const US* kL[3] = { ka, kb, kc };
    const US* qL[3] = { qa, qb, qc };

    const size_t sOff = ((size_t)b*S_ + sB + row16)*64 + (size_t)kblk*8;
    const size_t tOff = ((size_t)b*S_ + tB + row16)*64 + (size_t)kblk*8;

    short8 A[2][2][3], Bv[2][2][3];
    #pragma unroll
    for (int st = 0; st < 2; ++st)
        #pragma unroll
        for (int h = 0; h < 2; ++h)
            #pragma unroll
            for (int l = 0; l < 3; ++l) {
                A[st][h][l]  = *(const short8*)(kL[l] + sOff + st*1024 + h*32);
                Bv[st][h][l] = *(const short8*)(qL[l] + tOff + st*1024 + h*32);
            }

    #pragma unroll
    for (int st = 0; st < 2; ++st) {
        #pragma unroll
        for (int tt = 0; tt < 2; ++tt) {
            f32x4 acc[2];
            #pragma unroll
            for (int h = 0; h < 2; ++h) {
                f32x4 c = {0.f, 0.f, 0.f, 0.f};
                c = __builtin_amdgcn_mfma_f32_16x16x32_bf16(A[st][h][1], Bv[tt][h][1], c, 0,0,0);
                c = __builtin_amdgcn_mfma_f32_16x16x32_bf16(A[st][h][0], Bv[tt][h][2], c, 0,0,0);
                c = __builtin_amdgcn_mfma_f32_16x16x32_bf16(A[st][h][2], Bv[tt][h][0], c, 0,0,0);
                c = __builtin_amdgcn_mfma_f32_16x16x32_bf16(A[st][h][0], Bv[tt][h][1], c, 0,0,0);
                c = __builtin_amdgcn_mfma_f32_16x16x32_bf16(A[st][h][1], Bv[tt][h][0], c, 0,0,0);
                c = __builtin_amdgcn_mfma_f32_16x16x32_bf16(A[st][h][0], Bv[tt][h][0], c, 0,0,0);
                acc[h] = c;
            }
            u32* kout = keys + ((size_t)b*S_ + sB + st*16 + kblk*4)*S_
                             + tB + tt*16 + row16;
            #pragma unroll
            for (int r = 0; r < 4; ++r) {
                const float sc = w0*fmaxf(acc[0][r], 0.f) + w1*fmaxf(acc[1][r], 0.f);
                kout[(size_t)r*S_] = fkey(sc);
            }
        }
    }
}

// ---------------- Kernel 2b: exact top-256 per row ----------------
// One block (256 thr, 4 waves) per selection row. Keys staged in LDS,
// 4x8-bit radix with PER-WAVE histograms (4x lower atomic contention),
// redundant wave scan, two-phase ballot compaction; ties -> lowest index.
__global__ __launch_bounds__(256) void k_select(
    const u32* __restrict__ keys, int* __restrict__ top)
{
    __shared__ u32 kly[4096];
    __shared__ u32 hist[4][256];
    __shared__ u32 wcnt[8];

    const int tid = threadIdx.x, lane = tid & 63, w = tid >> 6;
    const size_t row = blockIdx.x;
    const u32* krow = keys + row * S_;

    #pragma unroll
    for (int i = 0; i < 4; ++i)
        ((uint4*)kly)[tid + i*256] = ((const uint4*)krow)[tid + i*256];
    __syncthreads();

    u32 prefix = 0; u32 krem = TK_;
    #pragma unroll 1
    for (int pass = 0; pass < 4; ++pass) {
        const int shift = 24 - 8*pass;
        ((uint4*)hist)[tid] = make_uint4(0u,0u,0u,0u);
        __syncthreads();
        #pragma unroll
        for (int i = 0; i < 16; ++i) {
            const u32 kk = kly[tid + i*256];
            const bool ok = (pass == 0) | ((kk >> (shift+8)) == prefix);
            if (ok) atomicAdd(&hist[w][(kk >> shift) & 255], 1u);
        }
        __syncthreads();
        const uint4 t0 = ((const uint4*)hist[0])[lane];
        const uint4 t1 = ((const uint4*)hist[1])[lane];
        const uint4 t2 = ((const uint4*)hist[2])[lane];
        const uint4 t3 = ((const uint4*)hist[3])[lane];
        uint4 h4;
        h4.x = t0.x + t1.x + t2.x + t3.x;
        h4.y = t0.y + t1.y + t2.y + t3.y;
        h4.z = t0.z + t1.z + t2.z + t3.z;
        h4.w = t0.w + t1.w + t2.w + t3.w;
        u32 ssum = h4.x + h4.y + h4.z + h4.w;
        #pragma unroll
        for (int off = 1; off < 64; off <<= 1) {
            const u32 tt = __shfl_down(ssum, off);
            if (lane + off < 64) ssum += tt;
        }
        u32 up = __shfl_down(ssum, 1);
        if (lane == 63) up = 0;
        const u32 a3 = up;
        const u32 a2 = a3 + h4.w;
        const u32 a1 = a2 + h4.z;
        const u32 a0 = a1 + h4.y;
        u32 binl = 0, nkl = 0; bool hit = false;
        if      (a0 < krem && a0 + h4.x >= krem) { hit = true; binl = 4*lane+0; nkl = krem - a0; }
        else if (a1 < krem && a1 + h4.y >= krem) { hit = true; binl = 4*lane+1; nkl = krem - a1; }
        else if (a2 < krem && a2 + h4.z >= krem) { hit = true; binl = 4*lane+2; nkl = krem - a2; }
        else if (a3 < krem && a3 + h4.w >= krem) { hit = true; binl = 4*lane+3; nkl = krem - a3; }
        const u64 mball = __ballot(hit);
        const int src = __ffsll(mball) - 1;
        const u32 bsel = __shfl(binl, src);
        krem = __shfl(nkl, src);
        prefix = (prefix << 8) | bsel;
        __syncthreads();
    }

    // ---- compaction ----
    const u32 T = prefix;
    const int G = TK_ - (int)krem;
    const u64 lmask = (lane == 0) ? 0ull : ((~0ull) >> (64 - lane));
    int cgt = 0, ceq = 0;
    #pragma unroll
    for (int i = 0; i < 16; ++i) {
        const u32 kk = kly[w*1024 + i*64 + lane];
        cgt += __popcll(__ballot(kk > T));
        ceq += __popcll(__ballot(kk == T));
    }
    if (lane == 0) { wcnt[w] = (u32)cgt; wcnt[4 + w] = (u32)ceq; }
    __syncthreads();
    int gts = 0, eqs = 0;
    for (int w2 = 0; w2 < 4; ++w2) {
        if (w2 < w) { gts += (int)wcnt[w2]; eqs += (int)wcnt[4 + w2]; }
    }
    int* orow = top + row * TK_;
    cgt = gts; ceq = eqs;
    #pragma unroll
    for (int i = 0; i < 16; ++i) {
        const int idx = w*1024 + i*64 + lane;
        const u32 kk = kly[idx];
        const bool gt = kk > T, eq = kk == T;
        const u64 mgt = __ballot(gt), meq = __ballot(eq);
        if (gt) orow[cgt + __popcll(mgt & lmask)] = idx;
        if (eq) {
            const int rk = ceq + __popcll(meq & lmask);
            if (rk < (int)krem) orow[G + rk] = idx;
        }
        cgt += __popcll(mgt); ceq += __popcll(meq);
    }
}

// ---------------- Kernel 3: gathered sparse attention ----------------
__global__ __launch_bounds__(256) void k_attn(
    const float* __restrict__ Q, const float* __restrict__ K,
    const float* __restrict__ V, const int* __restrict__ top,
    float* __restrict__ out)
{
    __shared__ int   il[256];
    __shared__ float qsm[8*64];
    __shared__ float wmat[8*256];
    __shared__ float opart[4*8*64];
    __shared__ float MZ[16];

    const int tid  = threadIdx.x;
    const int b    = blockIdx.x >> 12;
    const int s    = blockIdx.x & 4095;
    const int lane = tid & 63, w = tid >> 6;

    il[tid] = top[((size_t)(b*S_ + s))*TK_ + tid];
    qsm[tid]     = Q[((size_t)(b*HQ_ + (tid>>6)))*S_*64 + (size_t)s*64 + (tid&63)];
    qsm[256+tid] = Q[((size_t)(b*HQ_ + 4 + (tid>>6)))*S_*64 + (size_t)s*64 + (tid&63)];
    __syncthreads();

    const float* kp = K + ((size_t)(b*S_ + il[tid]))*64;
    float4 kx[16];
    #pragma unroll
    for (int g = 0; g < 16; ++g) kx[g] = *(const float4*)(kp + g*4);
    float sc[8];
    #pragma unroll
    for (int h = 0; h < 8; ++h) {
        float a = 0.f;
        #pragma unroll
        for (int g = 0; g < 16; ++g)
            a += dot4(*(const float4*)&qsm[h*64 + g*4], kx[g]);
        sc[h] = a * 0.125f;
    }
    #pragma unroll
    for (int h = 0; h < 8; ++h) wmat[h*256 + tid] = sc[h];
    __syncthreads();

    #pragma unroll
    for (int hh = 0; hh < 2; ++hh) {
        const int h = hh*4 + w;
        const float4 v4 = *(const float4*)&wmat[h*256 + lane*4];
        float mm = fmaxf(fmaxf(v4.x, v4.y), fmaxf(v4.z, v4.w));
        #pragma unroll
        for (int off = 32; off >= 1; off >>= 1) mm = fmaxf(mm, __shfl_xor(mm, off));
        if (lane == 0) MZ[h] = mm;
    }
    __syncthreads();
    #pragma unroll
    for (int h = 0; h < 8; ++h) wmat[h*256 + tid] = __expf(sc[h] - MZ[h]);
    __syncthreads();
    #pragma unroll
    for (int hh = 0; hh < 2; ++hh) {
        const int h = hh*4 + w;
        const float4 v4 = *(const float4*)&wmat[h*256 + lane*4];
        float ss = v4.x + v4.y + v4.z + v4.w;
        #pragma unroll
        for (int off = 32; off >= 1; off >>= 1) ss += __shfl_xor(ss, off);
        if (lane == 0) MZ[8 + h] = ss;
    }
    __syncthreads();

    const int dq = lane & 15, jsub = lane >> 4;
    float4 p[8];
    #pragma unroll
    for (int h = 0; h < 8; ++h) p[h] = make_float4(0.f,0.f,0.f,0.f);
    #pragma unroll
    for (int i = 0; i < 16; ++i) {
        const int j = w*64 + jsub*16 + i;
        const float4 v4 = *(const float4*)&V[((size_t)(b*S_ + il[j]))*64 + dq*4];
        #pragma unroll
        for (int h = 0; h < 8; ++h) {
            const float wv = wmat[h*256 + j];
            p[h].x += wv*v4.x; p[h].y += wv*v4.y;
            p[h].z += wv*v4.z; p[h].w += wv*v4.w;
        }
    }
    #pragma unroll
    for (int h = 0; h < 8; ++h) {
        p[h].x += __shfl_xor(p[h].x, 16); p[h].y += __shfl_xor(p[h].y, 16);
        p[h].z += __shfl_xor(p[h].z, 16); p[h].w += __shfl_xor(p[h].w, 16);
        p[h].x += __shfl_xor(p[h].x, 32); p[h].y += __shfl_xor(p[h].y, 32);
        p[h].z += __shfl_xor(p[h].z, 32); p[h].w += __shfl_xor(p[h].w, 32);
    }
    if (jsub == 0) {
        #pragma unroll
        for (int h = 0; h < 8; ++h)
            *(float4*)&opart[(w*8 + h)*64 + dq*4] = p[h];
    }
    __syncthreads();
    {
        const int h = tid >> 5, d0 = (tid & 31) * 2;
        float o0 = 0.f, o1 = 0.f;
        #pragma unroll
        for (int g = 0; g < 4; ++g) {
            o0 += opart[(g*8 + h)*64 + d0];
            o1 += opart[(g*8 + h)*64 + d0 + 1];
        }
        const float iz = 1.f / MZ[8 + h];
        *(float2*)&out[((size_t)(b*S_ + s))*512 + h*64 + d0] =
            make_float2(o0*iz, o1*iz);
    }
}

// ---------------- launcher ----------------
extern "C" void kernel_launch(void* const* d_in, const int* in_sizes, int n_in,
                              void* d_out, int out_size, void* d_ws, size_t ws_size,
                              hipStream_t stream) {
    const float* x  = (const float*)d_in[0];
    const float* Q  = (const float*)d_in[1];
    const float* K  = (const float*)d_in[2];
    const float* V  = (const float*)d_in[3];
    const float* Wq = (const float*)d_in[4];
    const float* bq = (const float*)d_in[5];
    const float* Wk = (const float*)d_in[6];
    const float* bk = (const float*)d_in[7];
    const float* lg = (const float*)d_in[8];
    const float* lb = (const float*)d_in[9];
    const float* iw = (const float*)d_in[10];
    float* out = (float*)d_out;

    char* ws = (char*)d_ws;
    int*  top = (int*)ws;                       // 8 MB
    US*   qa  = (US*)(ws + ( 8u<<20));          // 1 MB each
    US*   qb  = (US*)(ws + ( 9u<<20));
    US*   qc  = (US*)(ws + (10u<<20));
    US*   ka  = (US*)(ws + (11u<<20));
    US*   kb  = (US*)(ws + (12u<<20));
    US*   kc  = (US*)(ws + (13u<<20));
    u32* keys = (u32*)(ws + (16u<<20));         // 128 MB

    (void)in_sizes; (void)n_in; (void)out_size; (void)ws_size;

    k_proj_ln<<<dim3((B_*S_)/16), dim3(256), 0, stream>>>(
        x, Wq, bq, Wk, bk, lg, lb, qa, qb, qc, ka, kb, kc);
    k_scores_mfma<<<dim3(S_/64, (B_*S_)/64), dim3(256), 0, stream>>>(
        qa, qb, qc, ka, kb, kc, iw, keys);
    k_select<<<dim3(B_*S_), dim3(256), 0, stream>>>(keys, top);
    k_attn<<<dim3(B_*S_), dim3(256), 0, stream>>>(
        Q, K, V, top, out);
}

// Round 6
// 459.386 us; speedup vs baseline: 2.3437x; 1.1758x over previous
//
#include <hip/hip_runtime.h>
#include <math.h>

// DSA sparse attention, MI355X. Round 6: MFMA projection (3-limb exact
// bf16 split, LN fused in epilogue) + fused select+attn (top-k kept in LDS,
// no global top roundtrip). Scores kernel unchanged from R5 (verified).

#define B_   2
#define S_   4096
#define DM_  1024
#define HQ_  8
#define TK_  256

typedef unsigned int u32;
typedef unsigned long long u64;
typedef unsigned short US;
typedef __attribute__((ext_vector_type(8))) short short8;
typedef __attribute__((ext_vector_type(4))) float f32x4;

__device__ __forceinline__ float dot4(const float4 a, const float4 b) {
    return a.x*b.x + a.y*b.y + a.z*b.z + a.w*b.w;
}
// monotonic float->uint key
__device__ __forceinline__ u32 fkey(float f) {
    u32 b = __float_as_uint(f);
    return (b & 0x80000000u) ? ~b : (b | 0x80000000u);
}
// RNE round-to-bf16 helpers (bit-level; NaN not possible here)
__device__ __forceinline__ u32 bfbits(float f) {
    const u32 u = __float_as_uint(f);
    return (u + 0x7FFFu + ((u >> 16) & 1u)) >> 16;
}
__device__ __forceinline__ float bfval(u32 bits) {
    return __uint_as_float(bits << 16);
}
// exact 3-limb split: v = a + b + c + O(2^-25 rel)
__device__ __forceinline__ void split3(float v, US& a, US& b, US& c) {
    const u32 ab = bfbits(v); const float fa = bfval(ab);
    const float r1 = v - fa;                 // exact
    const u32 bb = bfbits(r1); const float fb = bfval(bb);
    const u32 cb = bfbits(r1 - fb);          // r1-fb exact
    a = (US)ab; b = (US)bb; c = (US)cb;
}

// ---------------- Kernel 0: W -> 3-limb bf16 ----------------
// wl layout: [3][128][1024] u16; rows 0..63 = Wq, 64..127 = Wk.
__global__ __launch_bounds__(256) void k_wsplit(
    const float* __restrict__ Wq, const float* __restrict__ Wk,
    US* __restrict__ wl)
{
    const int o   = blockIdx.x;            // 0..127
    const int tid = threadIdx.x;
    const float* src = (o < 64) ? (Wq + (size_t)o*DM_)
                                : (Wk + (size_t)(o-64)*DM_);
    const int k0 = tid * 4;
    const float4 v = *(const float4*)&src[k0];
    float vv[4] = {v.x, v.y, v.z, v.w};
    US aa[4], bb[4], cc[4];
    #pragma unroll
    for (int i = 0; i < 4; ++i) split3(vv[i], aa[i], bb[i], cc[i]);
    const size_t base = (size_t)o*DM_ + k0;
    *(ushort4*)&wl[0*131072 + base] = make_ushort4(aa[0],aa[1],aa[2],aa[3]);
    *(ushort4*)&wl[1*131072 + base] = make_ushort4(bb[0],bb[1],bb[2],bb[3]);
    *(ushort4*)&wl[2*131072 + base] = make_ushort4(cc[0],cc[1],cc[2],cc[3]);
}

// ---------------- Kernel 1: MFMA projection + LN + limb split ----------------
// 512 blocks x 256 thr (4 waves). Block = 16 rows x 128 stacked cols
// (0..63 q, 64..127 k). Wave w owns cols [w*32, w*32+32) = exactly one
// (mat, head) LN group. x staged per 256-k chunk, limb-split in LDS.
// 6-product exact-split MFMA (same scheme as k_scores_mfma, verified R5).
__global__ __launch_bounds__(256) void k_proj_mfma(
    const float* __restrict__ x, const US* __restrict__ wl,
    const float* __restrict__ bq, const float* __restrict__ bk,
    const float* __restrict__ lg, const float* __restrict__ lb,
    US* __restrict__ qa, US* __restrict__ qb, US* __restrict__ qc,
    US* __restrict__ ka, US* __restrict__ kb, US* __restrict__ kc)
{
    __shared__ US xl[3][16][264];          // +8 pad: 2-way-max conflicts
    const int tid   = threadIdx.x;
    const int w     = tid >> 6, lane = tid & 63;
    const int row16 = lane & 15, kblk = lane >> 4;
    const size_t s0 = (size_t)blockIdx.x * 16;

    f32x4 acc0 = {0.f,0.f,0.f,0.f};
    f32x4 acc1 = {0.f,0.f,0.f,0.f};

    const int srow = tid >> 4;             // staging: 16 thr per row
    const int scol = (tid & 15) * 16;

    for (int ck = 0; ck < 4; ++ck) {
        { // ---- stage x[16][256] chunk -> 3-limb LDS ----
            const float* xr = x + (s0 + srow)*DM_ + ck*256 + scol;
            #pragma unroll
            for (int q4 = 0; q4 < 4; ++q4) {
                const float4 v = *(const float4*)(xr + q4*4);
                float vv[4] = {v.x, v.y, v.z, v.w};
                US aa[4], bb[4], cc[4];
                #pragma unroll
                for (int i = 0; i < 4; ++i) split3(vv[i], aa[i], bb[i], cc[i]);
                const int cb = scol + q4*4;
                *(ushort4*)&xl[0][srow][cb] = make_ushort4(aa[0],aa[1],aa[2],aa[3]);
                *(ushort4*)&xl[1][srow][cb] = make_ushort4(bb[0],bb[1],bb[2],bb[3]);
                *(ushort4*)&xl[2][srow][cb] = make_ushort4(cc[0],cc[1],cc[2],cc[3]);
            }
        }
        __syncthreads();
        #pragma unroll
        for (int kt = 0; kt < 8; ++kt) {
            short8 A[3], B0[3], B1[3];
            #pragma unroll
            for (int l = 0; l < 3; ++l)
                A[l] = *(const short8*)&xl[l][row16][kt*32 + kblk*8];
            const size_t wko = (size_t)(ck*256 + kt*32 + kblk*8);
            #pragma unroll
            for (int l = 0; l < 3; ++l) {
                B0[l] = *(const short8*)&wl[(size_t)l*131072 + (size_t)(w*32 +      row16)*DM_ + wko];
                B1[l] = *(const short8*)&wl[(size_t)l*131072 + (size_t)(w*32 + 16 + row16)*DM_ + wko];
            }
            acc0 = __builtin_amdgcn_mfma_f32_16x16x32_bf16(A[1], B0[1], acc0, 0,0,0);
            acc0 = __builtin_amdgcn_mfma_f32_16x16x32_bf16(A[0], B0[2], acc0, 0,0,0);
            acc0 = __builtin_amdgcn_mfma_f32_16x16x32_bf16(A[2], B0[0], acc0, 0,0,0);
            acc0 = __builtin_amdgcn_mfma_f32_16x16x32_bf16(A[0], B0[1], acc0, 0,0,0);
            acc0 = __builtin_amdgcn_mfma_f32_16x16x32_bf16(A[1], B0[0], acc0, 0,0,0);
            acc0 = __builtin_amdgcn_mfma_f32_16x16x32_bf16(A[0], B0[0], acc0, 0,0,0);
            acc1 = __builtin_amdgcn_mfma_f32_16x16x32_bf16(A[1], B1[1], acc1, 0,0,0);
            acc1 = __builtin_amdgcn_mfma_f32_16x16x32_bf16(A[0], B1[2], acc1, 0,0,0);
            acc1 = __builtin_amdgcn_mfma_f32_16x16x32_bf16(A[2], B1[0], acc1, 0,0,0);
            acc1 = __builtin_amdgcn_mfma_f32_16x16x32_bf16(A[0], B1[1], acc1, 0,0,0);
            acc1 = __builtin_amdgcn_mfma_f32_16x16x32_bf16(A[1], B1[0], acc1, 0,0,0);
            acc1 = __builtin_amdgcn_mfma_f32_16x16x32_bf16(A[0], B1[0], acc1, 0,0,0);
        }
        __syncthreads();
    }

    // ---- epilogue: bias + LN (per 32-col wave group) + limb split ----
    const int c0 = w*32 + row16;           // stacked col, tile 0
    const int c1 = c0 + 16;                // tile 1
    const float bias0 = (w < 2) ? bq[c0] : bk[c0 - 64];
    const float bias1 = (w < 2) ? bq[c1] : bk[c1 - 64];
    const float gv0 = lg[c0 & 31], bv0 = lb[c0 & 31];
    const float gv1 = lg[c1 & 31], bv1 = lb[c1 & 31];
    US* __restrict__ oa = (w < 2) ? qa : ka;
    US* __restrict__ ob = (w < 2) ? qb : kb;
    US* __restrict__ oc = (w < 2) ? qc : kc;
    const int oc0 = c0 & 63, oc1 = c1 & 63;

    #pragma unroll
    for (int r = 0; r < 4; ++r) {
        const float v0 = acc0[r] + bias0;
        const float v1 = acc1[r] + bias1;
        float s1 = v0 + v1;
        float s2 = v0*v0 + v1*v1;
        #pragma unroll
        for (int off = 1; off < 16; off <<= 1) {
            s1 += __shfl_xor(s1, off);
            s2 += __shfl_xor(s2, off);
        }
        const float m   = s1 * (1.f/32.f);
        const float var = fmaxf(s2 * (1.f/32.f) - m*m, 0.f);
        const float inv = rsqrtf(var + 1e-5f);
        const float o0 = (v0 - m)*inv*gv0 + bv0;
        const float o1 = (v1 - m)*inv*gv1 + bv1;
        const size_t grow = s0 + (size_t)kblk*4 + r;
        US a0,b0,cl0, a1,b1,cl1;
        split3(o0, a0, b0, cl0);
        split3(o1, a1, b1, cl1);
        oa[grow*64 + oc0] = a0; ob[grow*64 + oc0] = b0; oc[grow*64 + oc0] = cl0;
        oa[grow*64 + oc1] = a1; ob[grow*64 + oc1] = b1; oc[grow*64 + oc1] = cl1;
    }
}

// ---------------- Kernel 2: MFMA score GEMM -> global keys (R5, verified) --
__global__ __launch_bounds__(256) void k_scores_mfma(
    const US* __restrict__ qa, const US* __restrict__ qb, const US* __restrict__ qc,
    const US* __restrict__ ka, const US* __restrict__ kb, const US* __restrict__ kc,
    const float* __restrict__ idxw, u32* __restrict__ keys)
{
    const int tid  = threadIdx.x;
    const int w    = tid >> 6, lane = tid & 63;
    const int row16 = lane & 15, kblk = lane >> 4;
    const int b    = blockIdx.y >> 6;
    const int sB   = (blockIdx.y & 63)*64 + (w >> 1)*32;
    const int tB   = blockIdx.x*64 + (w & 1)*32;
    const float w0 = idxw[0], w1 = idxw[1];

    const US* kL[3] = { ka, kb, kc };
    const US* qL[3] = { qa, qb, qc };

    const size_t sOff = ((size_t)b*S_ + sB + row16)*64 + (size_t)kblk*8;
    const size_t tOff = ((size_t)b*S_ + tB + row16)*64 + (size_t)kblk*8;

    short8 A[2][2][3], Bv[2][2][3];
    #pragma unroll
    for (int st = 0; st < 2; ++st)
        #pragma unroll
        for (int h = 0; h < 2; ++h)
            #pragma unroll
            for (int l = 0; l < 3; ++l) {
                A[st][h][l]  = *(const short8*)(kL[l] + sOff + st*1024 + h*32);
                Bv[st][h][l] = *(const short8*)(qL[l] + tOff + st*1024 + h*32);
            }

    #pragma unroll
    for (int st = 0; st < 2; ++st) {
        #pragma unroll
        for (int tt = 0; tt < 2; ++tt) {
            f32x4 acc[2];
            #pragma unroll
            for (int h = 0; h < 2; ++h) {
                f32x4 c = {0.f, 0.f, 0.f, 0.f};
                c = __builtin_amdgcn_mfma_f32_16x16x32_bf16(A[st][h][1], Bv[tt][h][1], c, 0,0,0);
                c = __builtin_amdgcn_mfma_f32_16x16x32_bf16(A[st][h][0], Bv[tt][h][2], c, 0,0,0);
                c = __builtin_amdgcn_mfma_f32_16x16x32_bf16(A[st][h][2], Bv[tt][h][0], c, 0,0,0);
                c = __builtin_amdgcn_mfma_f32_16x16x32_bf16(A[st][h][0], Bv[tt][h][1], c, 0,0,0);
                c = __builtin_amdgcn_mfma_f32_16x16x32_bf16(A[st][h][1], Bv[tt][h][0], c, 0,0,0);
                c = __builtin_amdgcn_mfma_f32_16x16x32_bf16(A[st][h][0], Bv[tt][h][0], c, 0,0,0);
                acc[h] = c;
            }
            u32* kout = keys + ((size_t)b*S_ + sB + st*16 + kblk*4)*S_
                             + tB + tt*16 + row16;
            #pragma unroll
            for (int r = 0; r < 4; ++r) {
                const float sc = w0*fmaxf(acc[0][r], 0.f) + w1*fmaxf(acc[1][r], 0.f);
                kout[(size_t)r*S_] = fkey(sc);
            }
        }
    }
}

// ---------------- Kernel 3: fused top-256 select + gathered attention ------
// One block (256 thr, 4 waves) per (b,s). Phase 1: radix top-256 into LDS
// il[256] (exact, ties -> lowest index). Phase 2: 8-head attention over the
// selected K/V rows. ~21.6 KB LDS (select keybuf reused by attn buffers).
__global__ __launch_bounds__(256) void k_sel_attn(
    const u32* __restrict__ keys,
    const float* __restrict__ Q, const float* __restrict__ K,
    const float* __restrict__ V, float* __restrict__ out)
{
    __shared__ __align__(16) char smemraw[20480];  // 16KB keys | 4KB hist
    __shared__ u32  wcnt[8];
    __shared__ int  il[256];
    __shared__ float MZ[16];

    u32* kly  = (u32*)smemraw;
    u32* hist = (u32*)(smemraw + 16384);           // [4][256] flat

    const int tid = threadIdx.x, lane = tid & 63, w = tid >> 6;
    const size_t row = blockIdx.x;
    const int b = (int)(row >> 12);
    const int s = (int)(row & 4095);

    // ---- phase 1: select ----
    {
        const u32* krow = keys + row * S_;
        #pragma unroll
        for (int i = 0; i < 4; ++i)
            ((uint4*)kly)[tid + i*256] = ((const uint4*)krow)[tid + i*256];
        __syncthreads();

        u32 prefix = 0; u32 krem = TK_;
        #pragma unroll 1
        for (int pass = 0; pass < 4; ++pass) {
            const int shift = 24 - 8*pass;
            ((uint4*)hist)[tid] = make_uint4(0u,0u,0u,0u);
            __syncthreads();
            #pragma unroll
            for (int i = 0; i < 16; ++i) {
                const u32 kk = kly[tid + i*256];
                const bool ok = (pass == 0) | ((kk >> (shift+8)) == prefix);
                if (ok) atomicAdd(&hist[w*256 + ((kk >> shift) & 255)], 1u);
            }
            __syncthreads();
            const uint4 t0 = ((const uint4*)(hist      ))[lane];
            const uint4 t1 = ((const uint4*)(hist + 256))[lane];
            const uint4 t2 = ((const uint4*)(hist + 512))[lane];
            const uint4 t3 = ((const uint4*)(hist + 768))[lane];
            uint4 h4;
            h4.x = t0.x + t1.x + t2.x + t3.x;
            h4.y = t0.y + t1.y + t2.y + t3.y;
            h4.z = t0.z + t1.z + t2.z + t3.z;
            h4.w = t0.w + t1.w + t2.w + t3.w;
            u32 ssum = h4.x + h4.y + h4.z + h4.w;
            #pragma unroll
            for (int off = 1; off < 64; off <<= 1) {
                const u32 tt = __shfl_down(ssum, off);
                if (lane + off < 64) ssum += tt;
            }
            u32 up = __shfl_down(ssum, 1);
            if (lane == 63) up = 0;
            const u32 a3 = up;
            const u32 a2 = a3 + h4.w;
            const u32 a1 = a2 + h4.z;
            const u32 a0 = a1 + h4.y;
            u32 binl = 0, nkl = 0; bool hit = false;
            if      (a0 < krem && a0 + h4.x >= krem) { hit = true; binl = 4*lane+0; nkl = krem - a0; }
            else if (a1 < krem && a1 + h4.y >= krem) { hit = true; binl = 4*lane+1; nkl = krem - a1; }
            else if (a2 < krem && a2 + h4.z >= krem) { hit = true; binl = 4*lane+2; nkl = krem - a2; }
            else if (a3 < krem && a3 + h4.w >= krem) { hit = true; binl = 4*lane+3; nkl = krem - a3; }
            const u64 mball = __ballot(hit);
            const int src = __ffsll(mball) - 1;
            const u32 bsel = __shfl(binl, src);
            krem = __shfl(nkl, src);
            prefix = (prefix << 8) | bsel;
            __syncthreads();
        }

        // compaction -> il[] in LDS
        const u32 T = prefix;
        const int G = TK_ - (int)krem;
        const u64 lmask = (lane == 0) ? 0ull : ((~0ull) >> (64 - lane));
        int cgt = 0, ceq = 0;
        #pragma unroll
        for (int i = 0; i < 16; ++i) {
            const u32 kk = kly[w*1024 + i*64 + lane];
            cgt += __popcll(__ballot(kk > T));
            ceq += __popcll(__ballot(kk == T));
        }
        if (lane == 0) { wcnt[w] = (u32)cgt; wcnt[4 + w] = (u32)ceq; }
        __syncthreads();
        int gts = 0, eqs = 0;
        for (int w2 = 0; w2 < 4; ++w2)
            if (w2 < w) { gts += (int)wcnt[w2]; eqs += (int)wcnt[4 + w2]; }
        cgt = gts; ceq = eqs;
        #pragma unroll
        for (int i = 0; i < 16; ++i) {
            const int idx = w*1024 + i*64 + lane;
            const u32 kk = kly[idx];
            const bool gt = kk > T, eq = kk == T;
            const u64 mgt = __ballot(gt), meq = __ballot(eq);
            if (gt) il[cgt + __popcll(mgt & lmask)] = idx;
            if (eq) {
                const int rk = ceq + __popcll(meq & lmask);
                if (rk < (int)krem) il[G + rk] = idx;
            }
            cgt += __popcll(mgt); ceq += __popcll(meq);
        }
    }
    __syncthreads();   // il complete; kly region free for attn buffers

    // ---- phase 2: attention ----
    float* qsm   = (float*)smemraw;          // 512 f
    float* wmat  = qsm + 512;                // 2048 f
    float* opart = qsm + 2560;               // 2048 f

    qsm[tid]     = Q[((size_t)(b*HQ_ + (tid>>6)))*S_*64 + (size_t)s*64 + (tid&63)];
    qsm[256+tid] = Q[((size_t)(b*HQ_ + 4 + (tid>>6)))*S_*64 + (size_t)s*64 + (tid&63)];
    __syncthreads();

    const float* kp = K + ((size_t)(b*S_ + il[tid]))*64;
    float4 kx[16];
    #pragma unroll
    for (int g = 0; g < 16; ++g) kx[g] = *(const float4*)(kp + g*4);
    float sc[8];
    #pragma unroll
    for (int h = 0; h < 8; ++h) {
        float a = 0.f;
        #pragma unroll
        for (int g = 0; g < 16; ++g)
            a += dot4(*(const float4*)&qsm[h*64 + g*4], kx[g]);
        sc[h] = a * 0.125f;
    }
    #pragma unroll
    for (int h = 0; h < 8; ++h) wmat[h*256 + tid] = sc[h];
    __syncthreads();

    #pragma unroll
    for (int hh = 0; hh < 2; ++hh) {
        const int h = hh*4 + w;
        const float4 v4 = *(const float4*)&wmat[h*256 + lane*4];
        float mm = fmaxf(fmaxf(v4.x, v4.y), fmaxf(v4.z, v4.w));
        #pragma unroll
        for (int off = 32; off >= 1; off >>= 1) mm = fmaxf(mm, __shfl_xor(mm, off));
        if (lane == 0) MZ[h] = mm;
    }
    __syncthreads();
    #pragma unroll
    for (int h = 0; h < 8; ++h) wmat[h*256 + tid] = __expf(sc[h] - MZ[h]);
    __syncthreads();
    #pragma unroll
    for (int hh = 0; hh < 2; ++hh) {
        const int h = hh*4 + w;
        const float4 v4 = *(const float4*)&wmat[h*256 + lane*4];
        float ss = v4.x + v4.y + v4.z + v4.w;
        #pragma unroll
        for (int off = 32; off >= 1; off >>= 1) ss += __shfl_xor(ss, off);
        if (lane == 0) MZ[8 + h] = ss;
    }
    __syncthreads();

    const int dq = lane & 15, jsub = lane >> 4;
    float4 p[8];
    #pragma unroll
    for (int h = 0; h < 8; ++h) p[h] = make_float4(0.f,0.f,0.f,0.f);
    #pragma unroll
    for (int i = 0; i < 16; ++i) {
        const int j = w*64 + jsub*16 + i;
        const float4 v4 = *(const float4*)&V[((size_t)(b*S_ + il[j]))*64 + dq*4];
        #pragma unroll
        for (int h = 0; h < 8; ++h) {
            const float wv = wmat[h*256 + j];
            p[h].x += wv*v4.x; p[h].y += wv*v4.y;
            p[h].z += wv*v4.z; p[h].w += wv*v4.w;
        }
    }
    #pragma unroll
    for (int h = 0; h < 8; ++h) {
        p[h].x += __shfl_xor(p[h].x, 16); p[h].y += __shfl_xor(p[h].y, 16);
        p[h].z += __shfl_xor(p[h].z, 16); p[h].w += __shfl_xor(p[h].w, 16);
        p[h].x += __shfl_xor(p[h].x, 32); p[h].y += __shfl_xor(p[h].y, 32);
        p[h].z += __shfl_xor(p[h].z, 32); p[h].w += __shfl_xor(p[h].w, 32);
    }
    if (jsub == 0) {
        #pragma unroll
        for (int h = 0; h < 8; ++h)
            *(float4*)&opart[(w*8 + h)*64 + dq*4] = p[h];
    }
    __syncthreads();
    {
        const int h = tid >> 5, d0 = (tid & 31) * 2;
        float o0 = 0.f, o1 = 0.f;
        #pragma unroll
        for (int g = 0; g < 4; ++g) {
            o0 += opart[(g*8 + h)*64 + d0];
            o1 += opart[(g*8 + h)*64 + d0 + 1];
        }
        const float iz = 1.f / MZ[8 + h];
        *(float2*)&out[((size_t)(b*S_ + s))*512 + h*64 + d0] =
            make_float2(o0*iz, o1*iz);
    }
}

// ---------------- launcher ----------------
extern "C" void kernel_launch(void* const* d_in, const int* in_sizes, int n_in,
                              void* d_out, int out_size, void* d_ws, size_t ws_size,
                              hipStream_t stream) {
    const float* x  = (const float*)d_in[0];
    const float* Q  = (const float*)d_in[1];
    const float* K  = (const float*)d_in[2];
    const float* V  = (const float*)d_in[3];
    const float* Wq = (const float*)d_in[4];
    const float* bq = (const float*)d_in[5];
    const float* Wk = (const float*)d_in[6];
    const float* bk = (const float*)d_in[7];
    const float* lg = (const float*)d_in[8];
    const float* lb = (const float*)d_in[9];
    const float* iw = (const float*)d_in[10];
    float* out = (float*)d_out;

    char* ws = (char*)d_ws;
    US*   wl  = (US*)ws;                        // 768 KB
    US*   qa  = (US*)(ws + ( 1u<<20));          // 1 MB each
    US*   qb  = (US*)(ws + ( 2u<<20));
    US*   qc  = (US*)(ws + ( 3u<<20));
    US*   ka  = (US*)(ws + ( 4u<<20));
    US*   kb  = (US*)(ws + ( 5u<<20));
    US*   kc  = (US*)(ws + ( 6u<<20));
    u32* keys = (u32*)(ws + (16u<<20));         // 128 MB

    (void)in_sizes; (void)n_in; (void)out_size; (void)ws_size;

    k_wsplit<<<dim3(128), dim3(256), 0, stream>>>(Wq, Wk, wl);
    k_proj_mfma<<<dim3((B_*S_)/16), dim3(256), 0, stream>>>(
        x, wl, bq, bk, lg, lb, qa, qb, qc, ka, kb, kc);
    k_scores_mfma<<<dim3(S_/64, (B_*S_)/64), dim3(256), 0, stream>>>(
        qa, qb, qc, ka, kb, kc, iw, keys);
    k_sel_attn<<<dim3(B_*S_), dim3(256), 0, stream>>>(
        keys, Q, K, V, out);
}